// Round 3
// baseline (4095.403 us; speedup 1.0000x reference)
//
#include <hip/hip_runtime.h>

#define NNODES 100000
#define NEDGES 3200000
#define NFEAT  512
#define NHID   256
#define NCLS   64
#define NLAYERS 8

typedef short s8v __attribute__((ext_vector_type(8)));   // 8 bf16 (4 VGPRs) MFMA A/B frag
typedef float f4v __attribute__((ext_vector_type(4)));   // 4 f32 MFMA C/D frag

__device__ __forceinline__ float bf2f(unsigned short u) {
    union { unsigned int i; float f; } v; v.i = ((unsigned int)u) << 16; return v.f;
}
__device__ __forceinline__ unsigned short f2bf(float f) {
    union { float f; unsigned int u; } v; v.f = f;
    unsigned int u = v.u;
    u += 0x7FFFu + ((u >> 16) & 1u);   // RNE
    return (unsigned short)(u >> 16);
}
// read element i of a harness float tensor whose storage dtype is decided by flag
__device__ __forceinline__ float ldf(const void* p, size_t i, int f32) {
    return f32 ? ((const float*)p)[i] : bf2f(((const unsigned short*)p)[i]);
}

// ---------------- dtype probe ----------------
// edge_w ~ U(0, 1/16). bf16 storage: every u16 in [0, 0x3D80]. f32 storage: even-index
// u16s are f32 mantissa-low garbage (uniform) -> w.h.p. sign bit set or > 0x3D80.
__global__ void probe_kernel(const unsigned short* __restrict__ ew, int* __restrict__ flag) {
    int i = threadIdx.x;                       // 64 threads
    unsigned short v = ew[2 * i];
    bool bad = (v & 0x8000u) || (v > 0x3D80u);
    unsigned long long m = __ballot(bad);
    if (i == 0) *flag = (m != 0ull) ? 1 : 0;   // 1 => float32 storage
}

// ---------------- CSR build ----------------
__global__ void hist_kernel(const int* __restrict__ row, int* __restrict__ counts) {
    int e = blockIdx.x * 256 + threadIdx.x;
    if (e < NEDGES) atomicAdd(&counts[row[e]], 1);
}

__global__ void scan_kernel(const int* __restrict__ counts, int* __restrict__ row_ptr,
                            int* __restrict__ cursor) {
    __shared__ int lds[1024];
    __shared__ int carry_s;
    const int tid = threadIdx.x;
    if (tid == 0) carry_s = 0;
    __syncthreads();
    for (int base = 0; base < NNODES; base += 1024) {
        int i = base + tid;
        int v = (i < NNODES) ? counts[i] : 0;
        lds[tid] = v;
        __syncthreads();
        for (int off = 1; off < 1024; off <<= 1) {
            int t = (tid >= off) ? lds[tid - off] : 0;
            __syncthreads();
            lds[tid] += t;
            __syncthreads();
        }
        int inc = lds[tid];
        int c = carry_s;
        if (i < NNODES) { row_ptr[i] = c + inc - v; cursor[i] = c + inc - v; }
        __syncthreads();
        if (tid == 1023) carry_s = c + inc;
        __syncthreads();
    }
    if (tid == 0) row_ptr[NNODES] = carry_s;
}

__global__ void scatter_kernel(const int* __restrict__ row, const int* __restrict__ col,
                               const void* __restrict__ w, int* __restrict__ cursor,
                               int* __restrict__ col_s, float* __restrict__ w_s,
                               const int* __restrict__ flagp) {
    const int f32 = *flagp;
    int e = blockIdx.x * 256 + threadIdx.x;
    if (e < NEDGES) {
        int r = row[e];
        int pos = atomicAdd(&cursor[r], 1);
        col_s[pos] = col[e];
        w_s[pos]  = ldf(w, e, f32);
    }
}

// ---------------- B-matrix repack into MFMA fragment order ----------------
// frag f = (ks*NT + nt)*64 + lane ; elem j -> B[ks*32 + (lane>>4)*8 + j][nt*16 + (lane&15)]
template<int K, int N>
__global__ void pack_b(const void* __restrict__ src, unsigned short* __restrict__ dst,
                       const int* __restrict__ flagp) {
    const int f32 = *flagp;
    const int NT = N / 16;
    const int total = (K / 32) * NT * 64;
    int tid = blockIdx.x * 256 + threadIdx.x;
    if (tid >= total) return;
    int lane = tid & 63, rest = tid >> 6;
    int nt = rest % NT, ks = rest / NT;
    int n  = nt * 16 + (lane & 15);
    int kb = ks * 32 + (lane >> 4) * 8;
    unsigned short tmp[8];
#pragma unroll
    for (int j = 0; j < 8; ++j) tmp[j] = f2bf(ldf(src, (size_t)(kb + j) * N + n, f32));
#pragma unroll
    for (int j = 0; j < 8; ++j) dst[(size_t)tid * 8 + j] = tmp[j];
}

// Wcomb_l = ((1-beta_l) I + beta_l W_l) @ W_sort  (256 x 64), packed B-frag layout, bf16.
__global__ void pack_wcomb(const void* __restrict__ Ws, const void* __restrict__ Wsort,
                           unsigned short* __restrict__ dst, const int* __restrict__ flagp) {
    const int f32 = *flagp;
    int tid = blockIdx.x * 256 + threadIdx.x;
    if (tid >= 16384) return;
    int lane = tid & 63;
    int rest = tid >> 6;
    int nt = rest & 3;
    int ks = (rest >> 2) & 7;
    int l  = rest >> 5;
    int n  = nt * 16 + (lane & 15);
    int kb = ks * 32 + (lane >> 4) * 8;
    float beta = 0.5f / (float)(l + 1);
    float ombeta = 1.0f - beta;
    const size_t wl = (size_t)l * NHID * NHID;
    unsigned short tmp[8];
#pragma unroll
    for (int j = 0; j < 8; ++j) {
        int k = kb + j;
        float s = 0.0f;
        for (int q = 0; q < NHID; ++q)
            s = fmaf(ldf(Ws, wl + (size_t)k * NHID + q, f32),
                     ldf(Wsort, (size_t)q * NCLS + n, f32), s);
        tmp[j] = f2bf(ombeta * ldf(Wsort, (size_t)k * NCLS + n, f32) + beta * s);
    }
#pragma unroll
    for (int j = 0; j < 8; ++j) dst[(size_t)tid * 8 + j] = tmp[j];
}

// ---------------- MFMA GEMM: out[M x N] (= / +=) A[M x K] * Bpacked (+ bias) ------------
// wave = 32 rows x full N. No LDS; b-frags are 16B loads from packed B (L1/L2-hot).
// ADYN: A is a harness tensor whose dtype follows the flag (f32 -> convert in-register).
template<int K, int NT, bool ADYN, bool ACCUM, bool BIAS, bool OUTBF>
__global__ __launch_bounds__(256) void gemm_mfma(
    const void* __restrict__ Av, const s8v* __restrict__ Bp,
    const void* __restrict__ bias,
    float* __restrict__ Cf, unsigned short* __restrict__ Cb,
    const int* __restrict__ flagp)
{
    const int f32 = (ADYN || BIAS) ? *flagp : 0;
    const int N    = NT * 16;
    const int lane = threadIdx.x & 63;
    const int wid  = threadIdx.x >> 6;
    const int job  = blockIdx.x * 4 + wid;
    const int mbase = job * 32;
    if (mbase >= NNODES) return;          // NNODES % 32 == 0: full tiles only
    const int l15  = lane & 15;
    const int quad = lane >> 4;

    f4v acc[2][NT];
#pragma unroll
    for (int mt = 0; mt < 2; ++mt)
#pragma unroll
        for (int nt = 0; nt < NT; ++nt)
            acc[mt][nt] = (f4v){0.f, 0.f, 0.f, 0.f};

    const int r0 = mbase + l15;
    const int r1 = mbase + 16 + l15;

    for (int ks = 0; ks < K / 32; ++ks) {
        const int kb = ks * 32 + quad * 8;
        s8v a0, a1;
        if (ADYN && f32) {
            const float* Af = (const float*)Av;
            const float4* p0 = (const float4*)(Af + (size_t)r0 * K + kb);
            const float4* p1 = (const float4*)(Af + (size_t)r1 * K + kb);
            float4 x0 = p0[0], x1 = p0[1];
            float4 y0 = p1[0], y1 = p1[1];
            a0[0] = (short)f2bf(x0.x); a0[1] = (short)f2bf(x0.y);
            a0[2] = (short)f2bf(x0.z); a0[3] = (short)f2bf(x0.w);
            a0[4] = (short)f2bf(x1.x); a0[5] = (short)f2bf(x1.y);
            a0[6] = (short)f2bf(x1.z); a0[7] = (short)f2bf(x1.w);
            a1[0] = (short)f2bf(y0.x); a1[1] = (short)f2bf(y0.y);
            a1[2] = (short)f2bf(y0.z); a1[3] = (short)f2bf(y0.w);
            a1[4] = (short)f2bf(y1.x); a1[5] = (short)f2bf(y1.y);
            a1[6] = (short)f2bf(y1.z); a1[7] = (short)f2bf(y1.w);
        } else {
            const unsigned short* A = (const unsigned short*)Av;
            a0 = *(const s8v*)(A + (size_t)r0 * K + kb);
            a1 = *(const s8v*)(A + (size_t)r1 * K + kb);
        }
#pragma unroll
        for (int nt = 0; nt < NT; ++nt) {
            s8v b = Bp[(ks * NT + nt) * 64 + lane];
            acc[0][nt] = __builtin_amdgcn_mfma_f32_16x16x32_bf16(a0, b, acc[0][nt], 0, 0, 0);
            acc[1][nt] = __builtin_amdgcn_mfma_f32_16x16x32_bf16(a1, b, acc[1][nt], 0, 0, 0);
        }
    }

#pragma unroll
    for (int mt = 0; mt < 2; ++mt) {
#pragma unroll
        for (int nt = 0; nt < NT; ++nt) {
#pragma unroll
            for (int r = 0; r < 4; ++r) {
                int row = mbase + mt * 16 + quad * 4 + r;   // C/D: row = quad*4+reg
                int col = nt * 16 + l15;                    //      col = lane&15
                float v = acc[mt][nt][r];
                if (BIAS) v += ldf(bias, col, f32);
                size_t idx = (size_t)row * N + col;
                if (OUTBF) {
                    Cb[idx] = f2bf(v);
                } else {
                    if (ACCUM) v += Cf[idx];
                    Cf[idx] = v;
                }
            }
        }
    }
}

// ---------------- SpMM + fused Xnext update ----------------
// one wave per node, 4 feats/lane; AX -> bf16 (GEMM A-operand), Xn = gamma*(Xc - AX)
template<bool LAST>
__global__ __launch_bounds__(256) void spmm_kernel(
    const int* __restrict__ row_ptr, const int* __restrict__ col_s,
    const float* __restrict__ w_s, const unsigned short* __restrict__ Xc,
    unsigned short* __restrict__ AXb, unsigned short* __restrict__ Xn,
    const void* __restrict__ gammas, int layer, const int* __restrict__ flagp)
{
    const int wid  = threadIdx.x >> 6;
    const int lane = threadIdx.x & 63;
    const int node = blockIdx.x * 4 + wid;
    if (node >= NNODES) return;
    const int start = row_ptr[node];
    const int end   = row_ptr[node + 1];
    const int fo    = lane * 4;
    float a0 = 0.f, a1 = 0.f, a2 = 0.f, a3 = 0.f;
    for (int e = start; e < end; ++e) {
        const int   c = col_s[e];
        const float w = w_s[e];
        ushort4 q = *(const ushort4*)(Xc + (size_t)c * NHID + fo);
        a0 = fmaf(w, bf2f(q.x), a0);
        a1 = fmaf(w, bf2f(q.y), a1);
        a2 = fmaf(w, bf2f(q.z), a2);
        a3 = fmaf(w, bf2f(q.w), a3);
    }
    ushort4 axo;
    axo.x = f2bf(a0); axo.y = f2bf(a1); axo.z = f2bf(a2); axo.w = f2bf(a3);
    *(ushort4*)(AXb + (size_t)node * NHID + fo) = axo;
    if (!LAST) {
        const float g = ldf(gammas, layer, *flagp);
        ushort4 xi = *(const ushort4*)(Xc + (size_t)node * NHID + fo);
        ushort4 xno;
        xno.x = f2bf(g * (bf2f(xi.x) - a0));
        xno.y = f2bf(g * (bf2f(xi.y) - a1));
        xno.z = f2bf(g * (bf2f(xi.z) - a2));
        xno.w = f2bf(g * (bf2f(xi.w) - a3));
        *(ushort4*)(Xn + (size_t)node * NHID + fo) = xno;
    }
}

// ---------------- log_softmax over 64 classes, one wave per row ----------------
__global__ __launch_bounds__(256) void lsm_kernel(const float* __restrict__ Z,
                                                  void* __restrict__ out,
                                                  const int* __restrict__ flagp) {
    const int f32 = *flagp;
    const int wid  = threadIdx.x >> 6;
    const int lane = threadIdx.x & 63;
    const int row  = blockIdx.x * 4 + wid;
    if (row >= NNODES) return;
    float z = Z[(size_t)row * NCLS + lane];
    float m = z;
#pragma unroll
    for (int off = 32; off >= 1; off >>= 1) m = fmaxf(m, __shfl_xor(m, off, 64));
    float s = __expf(z - m);
#pragma unroll
    for (int off = 32; off >= 1; off >>= 1) s += __shfl_xor(s, off, 64);
    float r = z - m - __logf(s);
    size_t idx = (size_t)row * NCLS + lane;
    if (f32) ((float*)out)[idx] = r;
    else     ((unsigned short*)out)[idx] = f2bf(r);
}

extern "C" void kernel_launch(void* const* d_in, const int* in_sizes, int n_in,
                              void* d_out, int out_size, void* d_ws, size_t ws_size,
                              hipStream_t stream)
{
    const void* X      = d_in[0];
    const int*  erow   = (const int*)d_in[1];
    const int*  ecol   = (const int*)d_in[2];
    const void* ew     = d_in[3];
    const void* Winit  = d_in[4];
    const void* binit  = d_in[5];
    const void* gammas = d_in[6];
    const void* Ws     = d_in[7];
    const void* Wsort  = d_in[8];
    const void* bsort  = d_in[9];

    // workspace layout (~207 MB total)
    char* p = (char*)d_ws;
    auto alloc = [&](size_t bytes) -> char* {
        char* r = p; p += (bytes + 255) & ~(size_t)255; return r;
    };
    int*            flag   = (int*)           alloc(256);
    float*          Zacc   = (float*)         alloc((size_t)NNODES * NCLS * 4);   // 25.6 MB
    unsigned short* Xc0    = (unsigned short*)alloc((size_t)NNODES * NHID * 2);   // 51.2 MB
    unsigned short* Xc1    = (unsigned short*)alloc((size_t)NNODES * NHID * 2);   // 51.2 MB
    unsigned short* AXb    = (unsigned short*)alloc((size_t)NNODES * NHID * 2);   // 51.2 MB
    int*            counts = (int*)           alloc((size_t)(NNODES + 1) * 4);
    int*            row_ptr= (int*)           alloc((size_t)(NNODES + 1) * 4);
    int*            cursor = (int*)           alloc((size_t)(NNODES + 1) * 4);
    int*            col_s  = (int*)           alloc((size_t)NEDGES * 4);          // 12.8 MB
    float*          w_s    = (float*)         alloc((size_t)NEDGES * 4);          // 12.8 MB
    unsigned short* WinitP = (unsigned short*)alloc((size_t)NFEAT * NHID * 2);
    unsigned short* WsortP = (unsigned short*)alloc((size_t)NHID * NCLS * 2);
    unsigned short* WcombP = (unsigned short*)alloc((size_t)NLAYERS * NHID * NCLS * 2);

    // dtype probe first — everything downstream branches on *flag
    probe_kernel<<<1, 64, 0, stream>>>((const unsigned short*)ew, flag);

    // CSR build (rebuilt every call)
    hipMemsetAsync(counts, 0, (size_t)NNODES * 4, stream);
    hist_kernel<<<NEDGES / 256, 256, 0, stream>>>(erow, counts);
    scan_kernel<<<1, 1024, 0, stream>>>(counts, row_ptr, cursor);
    scatter_kernel<<<NEDGES / 256, 256, 0, stream>>>(erow, ecol, ew, cursor, col_s, w_s, flag);

    // weight repack / precompute
    pack_b<NFEAT, NHID><<<64, 256, 0, stream>>>(Winit, WinitP, flag);   // 16384 frags
    pack_b<NHID, NCLS><<<8, 256, 0, stream>>>(Wsort, WsortP, flag);     //  2048 frags
    pack_wcomb<<<64, 256, 0, stream>>>(Ws, Wsort, WcombP, flag);        // 16384 frags

    const int gemm_grid = (NNODES / 32 + 3) / 4;   // 3125 wave-jobs -> 782 blocks

    // Xc0 = bf16(X @ W_init + b_init)   (A dtype follows flag)
    gemm_mfma<NFEAT, NHID / 16, true, false, true, true>
        <<<gemm_grid, 256, 0, stream>>>(X, (const s8v*)WinitP, binit, nullptr, Xc0, flag);

    // Zacc = Xc0 @ W_sort + b_sort   (f32)
    gemm_mfma<NHID, NCLS / 16, false, false, true, false>
        <<<gemm_grid, 256, 0, stream>>>(Xc0, (const s8v*)WsortP, bsort, Zacc, nullptr, flag);

    unsigned short* cur = Xc0;
    unsigned short* nxt = Xc1;
    for (int l = 0; l < NLAYERS; ++l) {
        if (l < NLAYERS - 1)
            spmm_kernel<false><<<NNODES / 4, 256, 0, stream>>>(row_ptr, col_s, w_s, cur, AXb, nxt, gammas, l, flag);
        else
            spmm_kernel<true><<<NNODES / 4, 256, 0, stream>>>(row_ptr, col_s, w_s, cur, AXb, nxt, gammas, l, flag);
        // Zacc += AXb @ Wcomb_l
        gemm_mfma<NHID, NCLS / 16, false, true, false, false>
            <<<gemm_grid, 256, 0, stream>>>(AXb, (const s8v*)WcombP + (size_t)l * 2048, nullptr, Zacc, nullptr, flag);
        unsigned short* t = cur; cur = nxt; nxt = t;
    }

    lsm_kernel<<<NNODES / 4, 256, 0, stream>>>(Zacc, d_out, flag);
}